// Round 3
// baseline (258.400 us; speedup 1.0000x reference)
//
#include <hip/hip_runtime.h>
#include <math.h>

#define PI_F 3.14159265358979323846f
#define TWO_PI_F 6.28318530717958647692f

// ---------------- sector map (matches reference _polar_masks) ----------------
__device__ __forceinline__ int sector_id(int hm, int wm) {
    const float step = 2.0f / 511.0f;               // linspace(-1,1,512) step
    float y = -1.0f + step * (float)hm;
    float x = -1.0f + step * (float)wm;
    float radius = sqrtf(x * x + y * y);
    float r = radius / sqrtf(2.0f);                 // radius.max() == sqrt(2) exactly
    float a = atan2f(y, x);
    a = fmodf(a, PI_F);
    if (a < 0.0f) a += PI_F;                        // jnp.remainder(angle, pi) -> [0, pi)

    const float rstep = (0.9f - 0.08f) / 3.0f;
    const float re0 = 0.08f;
    const float re1 = 0.08f + rstep;
    const float re2 = 0.08f + 2.0f * rstep;
    const float re3 = 0.9f;
    int rb;
    if      (r >= re0 && r < re1)  rb = 0;
    else if (r >= re1 && r < re2)  rb = 1;
    else if (r >= re2 && r <= re3) rb = 2;          // last radial bin inclusive
    else return -1;

    const float astep = PI_F / 8.0f;
    int ab = 7;                                     // last angular bin catches a >= t7
    #pragma unroll
    for (int i = 0; i < 7; ++i) {
        float t0 = astep * (float)i;
        float t1 = astep * (float)(i + 1);
        if (a >= t0 && a < t1) { ab = i; break; }
    }
    return rb * 8 + ab;
}

__device__ __forceinline__ float hannf(int i) {
    return 0.5f * (1.0f - __cosf(TWO_PI_F * (float)i / 511.0f));
}

// ---------------- 512-pt Stockham radix-2 FFT in LDS (forward) ----------------
__device__ __forceinline__ float2* fft512(float2* bufA, float2* bufB,
                                          const float2* tw, int t) {
    float2* src = bufA;
    float2* dst = bufB;
    #pragma unroll
    for (int stage = 0; stage < 9; ++stage) {
        int s = 1 << stage;
        int q = t & (s - 1);
        int p = t >> stage;
        float2 a = src[q + s * p];
        float2 b = src[q + s * p + 256];            // s*m == 256 at every stage
        float2 tv = tw[p << stage];
        float2 apb = make_float2(a.x + b.x, a.y + b.y);
        float dx = a.x - b.x, dy = a.y - b.y;
        float2 twv = make_float2(dx * tv.x - dy * tv.y, dx * tv.y + dy * tv.x);
        dst[q + 2 * s * p] = apb;
        dst[q + 2 * s * p + s] = twv;
        __syncthreads();
        float2* tmp = src; src = dst; dst = tmp;
    }
    return src;
}

// ---------------- kernel 1: zero the accumulators ----------------
__global__ void zero_kernel(float* p, int n) {
    int i = blockIdx.x * 256 + threadIdx.x;
    if (i < n) p[i] = 0.0f;
}

// ---------------- kernel 2: luma + window + row FFT (2 real rows packed) ----------------
// Also computes 32 entries of the sector map (transposed: mapT[wm*512+hm]) and
// the sector pixel counts, folded in so the standalone map kernel disappears.
__global__ __launch_bounds__(256) void rowfft_kernel(const float* __restrict__ pred,
                                                     const float* __restrict__ tgt,
                                                     float2* __restrict__ buf,
                                                     unsigned char* __restrict__ mapT,
                                                     float* __restrict__ counts) {
    __shared__ float2 lds[2][512];
    __shared__ float2 tw[256];
    __shared__ float cbins[24];
    int blk = blockIdx.x;                           // 32*256 = 8192
    int img = blk >> 8;
    int hp = blk & 255;
    int h0 = 2 * hp, h1 = h0 + 1;
    int t = threadIdx.x;
    if (t < 24) cbins[t] = 0.0f;
    {
        float sn, cs;
        __sincosf(-TWO_PI_F * (float)t / 512.0f, &sn, &cs);
        tw[t] = make_float2(cs, sn);
    }
    const float* base = (img < 16) ? (pred + (size_t)img * 3 * 262144)
                                   : (tgt  + (size_t)(img - 16) * 3 * 262144);
    float wh0 = hannf(h0), wh1 = hannf(h1);
    #pragma unroll
    for (int k = 0; k < 2; ++k) {
        int w = t + k * 256;
        float ww = hannf(w);
        size_t off0 = (size_t)h0 * 512 + w;
        size_t off1 = off0 + 512;
        float l0 = 0.2989f * base[off0] + 0.587f * base[262144 + off0] + 0.114f * base[524288 + off0];
        float l1 = 0.2989f * base[off1] + 0.587f * base[262144 + off1] + 0.114f * base[524288 + off1];
        lds[0][w] = make_float2(l0 * (wh0 * ww), l1 * (wh1 * ww));
    }
    // folded map/counts work: 32 pixels per block covers 8192*32 = 262144
    if (t < 32) {
        int idx = blk * 32 + t;                     // idx = wm*512 + hm
        int wm = idx >> 9, hm = idx & 511;
        int s = sector_id(hm, wm);
        mapT[idx] = (unsigned char)(s < 0 ? 255 : s);
        if (s >= 0) atomicAdd(&cbins[s], 1.0f);
    }
    __syncthreads();
    float2* res = fft512(lds[0], lds[1], tw, t);
    size_t obase = (size_t)img * 257 * 512;
    {
        int k = t;                                  // k in [0,255]
        float2 zk = res[k];
        float2 zm = res[(512 - k) & 511];
        // A[k] = (Z[k]+conj(Z[-k]))/2 ; B[k] = -i(Z[k]-conj(Z[-k]))/2
        float4 o = make_float4(0.5f * (zk.x + zm.x), 0.5f * (zk.y - zm.y),
                               0.5f * (zk.y + zm.y), 0.5f * (zm.x - zk.x));
        ((float4*)buf)[(obase + (size_t)k * 512 + h0) >> 1] = o;
    }
    if (t == 0) {                                   // k = 256: self-conjugate index
        float2 z = res[256];
        float4 o = make_float4(z.x, 0.0f, z.y, 0.0f);
        ((float4*)buf)[(obase + (size_t)256 * 512 + h0) >> 1] = o;
    }
    // cbins were written before fft barriers; visible now
    if (t < 24) {
        float c = cbins[t];
        if (c != 0.0f) atomicAdd(&counts[t], c);
    }
}

// ---------------- kernel 3: column FFT + log-mag + sector reduction ----------------
// One block per (img, w), w in [0,256]. Hermitian mirror covers w in [257,511].
// bins replicated 16x with stride 25: 25*r mod 32 is injective for r in [0,16),
// so the 16 replicas of one bin live in 16 distinct LDS banks -> same-address
// atomic serialization drops from ~64-way to ~4-way.
#define NREP 16
#define RSTRIDE 25
__global__ __launch_bounds__(256) void colfft_kernel(const float2* __restrict__ buf,
                                                     const unsigned char* __restrict__ mapT,
                                                     float* __restrict__ acc) {
    __shared__ float2 lds[2][512];
    __shared__ float2 tw[256];
    __shared__ float bins[NREP * RSTRIDE];
    int blk = blockIdx.x;
    int img = blk / 257;
    int w = blk % 257;
    int t = threadIdx.x;
    for (int i = t; i < NREP * RSTRIDE; i += 256) bins[i] = 0.0f;
    {
        float sn, cs;
        __sincosf(-TWO_PI_F * (float)t / 512.0f, &sn, &cs);
        tw[t] = make_float2(cs, sn);
    }
    const float2* col = buf + (size_t)(img * 257 + w) * 512;
    lds[0][t] = col[t];
    lds[0][t + 256] = col[t + 256];
    __syncthreads();
    float2* res = fft512(lds[0], lds[1], tw, t);
    int rep = (t & (NREP - 1)) * RSTRIDE;
    bool mir = (w >= 1 && w <= 255);
    int wm = (w + 256) & 511;                       // fftshift via index remap
    int wm2 = (256 - w) & 511;                      // shifted coord of column 512-w
    const unsigned char* mcol  = mapT + (size_t)wm * 512;
    const unsigned char* mcol2 = mapT + (size_t)wm2 * 512;
    #pragma unroll
    for (int k = 0; k < 2; ++k) {
        int h = t + k * 256;
        float2 v = res[h];
        float mag = log1pf(sqrtf(v.x * v.x + v.y * v.y));
        int hm = (h + 256) & 511;
        int s = mcol[hm];
        if (s < 24) atomicAdd(&bins[rep + s], mag);
        if (mir) {
            int hm2 = (256 - h) & 511;              // shifted coord of row (512-h)&511
            int s2 = mcol2[hm2];
            if (s2 < 24) atomicAdd(&bins[rep + s2], mag);  // |F[-h,-w]| == |F[h,w]|
        }
    }
    __syncthreads();
    if (t < 24) {
        float sum = 0.0f;
        #pragma unroll
        for (int r = 0; r < NREP; ++r) sum += bins[r * RSTRIDE + t];
        atomicAdd(&acc[img * 24 + t], sum);
    }
}

// ---------------- kernel 4: energies -> charbonnier -> weighted mean ----------------
__global__ __launch_bounds__(384) void final_kernel(const float* __restrict__ acc,
                                                    const float* __restrict__ counts,
                                                    const float* __restrict__ rw,
                                                    float* __restrict__ out) {
    __shared__ float ep[384], et[384], red[384];
    int t = threadIdx.x;                            // t = b*24 + r*8 + a
    int b = t / 24;
    int s = t % 24;
    int r = s >> 3;
    float cnt = fmaxf(counts[s], 1e-6f);
    ep[t] = acc[b * 24 + s] / cnt;
    et[t] = acc[(16 + b) * 24 + s] / cnt;
    __syncthreads();
    int gbase = b * 24 + r * 8;
    float sp = 0.0f, st = 0.0f;
    #pragma unroll
    for (int a = 0; a < 8; ++a) { sp += ep[gbase + a]; st += et[gbase + a]; }
    float pe = ep[t] / fmaxf(sp, 1e-6f);
    float te = et[t] / fmaxf(st, 1e-6f);
    float d = pe - te;
    float dist = sqrtf(d * d + 1e-6f);
    red[t] = dist * rw[r];
    __syncthreads();
    if (t < 128) red[t] += red[t + 128] + red[t + 256];
    __syncthreads();
    if (t < 64) {
        float v = red[t] + red[t + 64];
        #pragma unroll
        for (int o = 32; o > 0; o >>= 1) v += __shfl_down(v, o, 64);
        if (t == 0) out[0] = v / 384.0f;
    }
}

extern "C" void kernel_launch(void* const* d_in, const int* in_sizes, int n_in,
                              void* d_out, int out_size, void* d_ws, size_t ws_size,
                              hipStream_t stream) {
    const float* pred = (const float*)d_in[0];
    const float* tgt  = (const float*)d_in[1];
    const float* rw   = (const float*)d_in[2];

    char* ws = (char*)d_ws;
    float* acc    = (float*)ws;                     // 32*24 floats
    float* counts = acc + 32 * 24;                  // 24 floats
    unsigned char* mapT = (unsigned char*)(ws + 4096);      // 512*512 = 256 KB
    float2* buf   = (float2*)(ws + 4096 + 262144);  // 32*257*512 complex = 33.7 MB

    zero_kernel<<<4, 256, 0, stream>>>(acc, 32 * 24 + 24);
    rowfft_kernel<<<32 * 256, 256, 0, stream>>>(pred, tgt, buf, mapT, counts);
    colfft_kernel<<<32 * 257, 256, 0, stream>>>(buf, mapT, acc);
    final_kernel<<<1, 384, 0, stream>>>(acc, counts, rw, (float*)d_out);
}

// Round 4
// 205.122 us; speedup vs baseline: 1.2597x; 1.2597x over previous
//
#include <hip/hip_runtime.h>
#include <math.h>

#define PI_F 3.14159265358979323846f
#define TWO_PI_F 6.28318530717958647692f
#define RSQ2 0.70710678118654752440f

// wave-synchronous LDS fence: waits this wave's own DS ops; memory clobber
// stops the compiler from moving LDS accesses across it. Each wave owns a
// private LDS region, so no s_barrier is needed.
#define WAVE_SYNC() __asm__ volatile("s_waitcnt lgkmcnt(0)" ::: "memory")
// additive swizzle: injective on [0,512), max 574; breaks the 2-bank
// degeneracy of the stage-0 write pattern (8j+i).
#define LADDR(a) ((a) + ((a) >> 3))

__device__ __forceinline__ float2 cadd(float2 a, float2 b){ return make_float2(a.x+b.x, a.y+b.y); }
__device__ __forceinline__ float2 csub(float2 a, float2 b){ return make_float2(a.x-b.x, a.y-b.y); }
__device__ __forceinline__ float2 cmul(float2 a, float2 b){ return make_float2(a.x*b.x - a.y*b.y, a.x*b.y + a.y*b.x); }
__device__ __forceinline__ float2 cw1(float2 a){ return make_float2(RSQ2*(a.x+a.y), RSQ2*(a.y-a.x)); }  // *W8^1
__device__ __forceinline__ float2 cw2(float2 a){ return make_float2(a.y, -a.x); }                        // *(-i)
__device__ __forceinline__ float2 cw3(float2 a){ return make_float2(RSQ2*(a.y-a.x), -RSQ2*(a.x+a.y)); }  // *W8^3

// in-place DIF-8. On return, slot m holds U_{br[m]}, br = {0,4,2,6,1,5,3,7}.
// Verified by hand on impulse (U_k = W8^k) and DC (U = 8*delta_0) inputs.
__device__ __forceinline__ void dft8(float2* v){
    float2 a0=cadd(v[0],v[4]), a1=cadd(v[1],v[5]), a2=cadd(v[2],v[6]), a3=cadd(v[3],v[7]);
    float2 b0=csub(v[0],v[4]);
    float2 b1=cw1(csub(v[1],v[5]));
    float2 b2=cw2(csub(v[2],v[6]));
    float2 b3=cw3(csub(v[3],v[7]));
    float2 c0=cadd(a0,a2), c2=csub(a0,a2), c1=cadd(a1,a3), c3=cw2(csub(a1,a3));
    float2 d0=cadd(b0,b2), d2=csub(b0,b2), d1=cadd(b1,b3), d3=cw2(csub(b1,b3));
    v[0]=cadd(c0,c1); v[1]=csub(c0,c1);   // U0, U4
    v[2]=cadd(c2,c3); v[3]=csub(c2,c3);   // U2, U6
    v[4]=cadd(d0,d1); v[5]=csub(d0,d1);   // U1, U5
    v[6]=cadd(d2,d3); v[7]=csub(d2,d3);   // U3, U7
}

// Stockham radix-8 stage store: address-slot c gets U_c * w1^c at base+step*c.
// (slot br[c] holds U_c; w1 = W_512^{s*p}.)
__device__ __forceinline__ void stage_store(float2* wl, const float2* v, float2 w1,
                                            int base, int step){
    constexpr int br[8] = {0,4,2,6,1,5,3,7};
    wl[LADDR(base)] = v[0];
    float2 p = w1;
    #pragma unroll
    for (int c = 1; c < 8; ++c) {
        wl[LADDR(base + step*c)] = cmul(v[br[c]], p);
        p = cmul(p, w1);
    }
}

__device__ __forceinline__ void stage_load(const float2* wl, float2* v, int j){
    #pragma unroll
    for (int i = 0; i < 8; ++i) v[i] = wl[LADDR(j + 64*i)];
}

// ---------------- sector map (matches reference _polar_masks) ----------------
__device__ __forceinline__ int sector_id(int hm, int wm) {
    const float step = 2.0f / 511.0f;
    float y = -1.0f + step * (float)hm;
    float x = -1.0f + step * (float)wm;
    float radius = sqrtf(x * x + y * y);
    float r = radius / sqrtf(2.0f);
    float a = atan2f(y, x);
    a = fmodf(a, PI_F);
    if (a < 0.0f) a += PI_F;

    const float rstep = (0.9f - 0.08f) / 3.0f;
    const float re0 = 0.08f;
    const float re1 = 0.08f + rstep;
    const float re2 = 0.08f + 2.0f * rstep;
    const float re3 = 0.9f;
    int rb;
    if      (r >= re0 && r < re1)  rb = 0;
    else if (r >= re1 && r < re2)  rb = 1;
    else if (r >= re2 && r <= re3) rb = 2;
    else return -1;

    const float astep = PI_F / 8.0f;
    int ab = 7;
    #pragma unroll
    for (int i = 0; i < 7; ++i) {
        float t0 = astep * (float)i;
        float t1 = astep * (float)(i + 1);
        if (a >= t0 && a < t1) { ab = i; break; }
    }
    return rb * 8 + ab;
}

__device__ __forceinline__ float hannf(int i) {
    return 0.5f * (1.0f - __cosf(TWO_PI_F * (float)i / 511.0f));
}

// ---------------- kernel 1: zero the accumulators ----------------
__global__ void zero_kernel(float* p, int n) {
    int i = blockIdx.x * 256 + threadIdx.x;
    if (i < n) p[i] = 0.0f;
}

// ---------------- kernel 2: luma + window + row FFT, radix-8 wave-sync ----------------
// Block = 4 waves; each wave FFTs one packed row-pair (h0 real, h1 imag).
// Map/counts generation folded in (128 px/block). Output layout [img][k][h], k<=256.
__global__ __launch_bounds__(256) void rowfft_kernel(const float* __restrict__ pred,
                                                     const float* __restrict__ tgt,
                                                     float4* __restrict__ out4,
                                                     unsigned char* __restrict__ mapT,
                                                     float* __restrict__ counts) {
    __shared__ float2 lds[4 * 576];
    __shared__ float cbins[24];
    int blk = blockIdx.x;                 // 32 img * 64
    int img = blk >> 6;
    int pb  = blk & 63;
    int t = threadIdx.x;
    int wv = t >> 6, j = t & 63;
    int hp = pb * 4 + wv;                 // row-pair index [0,256)
    int h0 = 2 * hp;
    float2* wl = lds + wv * 576;

    if (t < 24) cbins[t] = 0.0f;
    __syncthreads();
    if (t < 128) {                        // folded sector map + counts
        int idx = blk * 128 + t;          // idx = wm*512 + hm
        int wm = idx >> 9, hm = idx & 511;
        int s = sector_id(hm, wm);
        mapT[idx] = (unsigned char)(s < 0 ? 255 : s);
        if (s >= 0) atomicAdd(&cbins[s], 1.0f);
    }

    const float* base = (img < 16) ? (pred + (size_t)img * 786432)
                                   : (tgt  + (size_t)(img - 16) * 786432);
    float wh0 = hannf(h0), wh1 = hannf(h0 + 1);
    float2 v[8];
    #pragma unroll
    for (int i = 0; i < 8; ++i) {
        int w = j + 64 * i;
        float ww = hannf(w);
        size_t off0 = (size_t)h0 * 512 + w;
        size_t off1 = off0 + 512;
        float l0 = 0.2989f*base[off0] + 0.587f*base[off0+262144] + 0.114f*base[off0+524288];
        float l1 = 0.2989f*base[off1] + 0.587f*base[off1+262144] + 0.114f*base[off1+524288];
        v[i] = make_float2(l0 * (wh0 * ww), l1 * (wh1 * ww));
    }
    float sn, cs;
    // stage 0: s=1, p=j, write 8j+c
    dft8(v);
    __sincosf(-TWO_PI_F * (float)j / 512.0f, &sn, &cs);
    stage_store(wl, v, make_float2(cs, sn), 8 * j, 1);
    WAVE_SYNC();
    // stage 1: s=8, q=j&7, p=j>>3, write q+64p+8c, twiddle W^{8p*c}
    stage_load(wl, v, j);
    WAVE_SYNC();
    dft8(v);
    __sincosf(-TWO_PI_F * (float)((j >> 3) << 3) / 512.0f, &sn, &cs);
    stage_store(wl, v, make_float2(cs, sn), (j & 7) + 64 * (j >> 3), 8);
    WAVE_SYNC();
    // stage 2: s=64, p=0 -> no twiddle; result in regs: Z[j+64c] = v[br[c]]
    stage_load(wl, v, j);
    dft8(v);
    constexpr int br[8] = {0,4,2,6,1,5,3,7};
    size_t kbase = (size_t)img * 257;
    int partner = (64 - j) & 63;
    // Hermitian unpack: Z[512-k]: lane 64-j slot 7-c (j>0) / lane 0 slot (8-c)&7 (j==0)
    #pragma unroll
    for (int c = 0; c < 4; ++c) {
        float2 zk = v[br[c]];
        float mx = __shfl(v[br[7 - c]].x, partner, 64);
        float my = __shfl(v[br[7 - c]].y, partner, 64);
        float2 zs = v[br[(8 - c) & 7]];
        float2 zm = make_float2(j == 0 ? zs.x : mx, j == 0 ? zs.y : my);
        int k = j + 64 * c;
        float4 o = make_float4(0.5f*(zk.x+zm.x), 0.5f*(zk.y-zm.y),
                               0.5f*(zk.y+zm.y), 0.5f*(zm.x-zk.x));
        out4[(kbase + k) * 256 + hp] = o;
    }
    if (j == 0) {                         // k = 256 (self-conjugate)
        float2 z = v[br[4]];
        out4[(kbase + 256) * 256 + hp] = make_float4(z.x, 0.0f, z.y, 0.0f);
    }
    __syncthreads();
    if (t < 24) {
        float c = cbins[t];
        if (c != 0.0f) atomicAdd(&counts[t], c);
    }
}

// ---------------- kernel 3: column FFT + log-mag + sector bins, radix-8 wave-sync ----------------
// One wave per (img, w) column, w in [0,256]; Hermitian mirror covers [257,511].
// Per-wave bins with 8 bank-spread replicas; no block barrier at all.
__global__ __launch_bounds__(256) void colfft_kernel(const float2* __restrict__ buf,
                                                     const unsigned char* __restrict__ mapT,
                                                     float* __restrict__ acc) {
    __shared__ float2 lds[4 * 576];
    __shared__ float bins[4 * 200];
    int t = threadIdx.x;
    int wv = t >> 6, j = t & 63;
    int gid = blockIdx.x * 4 + wv;        // 0 .. 8223
    int img = gid / 257;
    int w = gid - img * 257;
    float2* wl = lds + wv * 576;
    float* wb = bins + wv * 200;
    #pragma unroll
    for (int i = 0; i < 4; ++i) {
        int ii = j + 64 * i;
        if (ii < 200) wb[ii] = 0.0f;
    }
    const float2* col = buf + (size_t)gid * 512;
    float2 v[8];
    #pragma unroll
    for (int i = 0; i < 8; ++i) v[i] = col[j + 64 * i];
    float sn, cs;
    dft8(v);
    __sincosf(-TWO_PI_F * (float)j / 512.0f, &sn, &cs);
    stage_store(wl, v, make_float2(cs, sn), 8 * j, 1);
    WAVE_SYNC();
    stage_load(wl, v, j);
    WAVE_SYNC();
    dft8(v);
    __sincosf(-TWO_PI_F * (float)((j >> 3) << 3) / 512.0f, &sn, &cs);
    stage_store(wl, v, make_float2(cs, sn), (j & 7) + 64 * (j >> 3), 8);
    WAVE_SYNC();
    stage_load(wl, v, j);
    dft8(v);
    constexpr int br[8] = {0,4,2,6,1,5,3,7};
    const unsigned char* mw  = mapT + (size_t)((w + 256) & 511) * 512;
    const unsigned char* mw2 = mapT + (size_t)((256 - w) & 511) * 512;
    bool mir = (w >= 1 && w <= 255);
    int rep = (j & 7) * 25;               // 25*r mod 32 distinct for r in [0,8)
    #pragma unroll
    for (int c = 0; c < 8; ++c) {
        float2 z = v[br[c]];              // Z[h = j + 64c]
        float mag = log1pf(sqrtf(z.x * z.x + z.y * z.y));
        int hm = j + 64 * ((c + 4) & 7);  // (h+256)&511
        int s1 = mw[hm];
        if (s1 < 24) atomicAdd(&wb[rep + s1], mag);
        if (mir) {
            int hm2 = (256 - (j + 64 * c)) & 511;
            int s2 = mw2[hm2];
            if (s2 < 24) atomicAdd(&wb[rep + s2], mag);
        }
    }
    WAVE_SYNC();
    if (j < 24) {
        float sum = 0.0f;
        #pragma unroll
        for (int r = 0; r < 8; ++r) sum += wb[r * 25 + j];
        atomicAdd(&acc[img * 24 + j], sum);
    }
}

// ---------------- kernel 4: energies -> charbonnier -> weighted mean ----------------
__global__ __launch_bounds__(384) void final_kernel(const float* __restrict__ acc,
                                                    const float* __restrict__ counts,
                                                    const float* __restrict__ rw,
                                                    float* __restrict__ out) {
    __shared__ float ep[384], et[384], red[384];
    int t = threadIdx.x;                  // t = b*24 + r*8 + a
    int b = t / 24;
    int s = t % 24;
    int r = s >> 3;
    float cnt = fmaxf(counts[s], 1e-6f);
    ep[t] = acc[b * 24 + s] / cnt;
    et[t] = acc[(16 + b) * 24 + s] / cnt;
    __syncthreads();
    int gbase = b * 24 + r * 8;
    float sp = 0.0f, st = 0.0f;
    #pragma unroll
    for (int a = 0; a < 8; ++a) { sp += ep[gbase + a]; st += et[gbase + a]; }
    float pe = ep[t] / fmaxf(sp, 1e-6f);
    float te = et[t] / fmaxf(st, 1e-6f);
    float d = pe - te;
    float dist = sqrtf(d * d + 1e-6f);
    red[t] = dist * rw[r];
    __syncthreads();
    if (t < 128) red[t] += red[t + 128] + red[t + 256];
    __syncthreads();
    if (t < 64) {
        float v = red[t] + red[t + 64];
        #pragma unroll
        for (int o = 32; o > 0; o >>= 1) v += __shfl_down(v, o, 64);
        if (t == 0) out[0] = v / 384.0f;
    }
}

extern "C" void kernel_launch(void* const* d_in, const int* in_sizes, int n_in,
                              void* d_out, int out_size, void* d_ws, size_t ws_size,
                              hipStream_t stream) {
    const float* pred = (const float*)d_in[0];
    const float* tgt  = (const float*)d_in[1];
    const float* rw   = (const float*)d_in[2];

    char* ws = (char*)d_ws;
    float* acc    = (float*)ws;                     // 32*24 floats
    float* counts = acc + 32 * 24;                  // 24 floats
    unsigned char* mapT = (unsigned char*)(ws + 4096);      // 512*512 = 256 KB
    float2* buf   = (float2*)(ws + 4096 + 262144);  // 32*257*512 complex = 33.7 MB

    zero_kernel<<<4, 256, 0, stream>>>(acc, 32 * 24 + 24);
    rowfft_kernel<<<32 * 64, 256, 0, stream>>>(pred, tgt, (float4*)buf, mapT, counts);
    colfft_kernel<<<2056, 256, 0, stream>>>(buf, mapT, acc);
    final_kernel<<<1, 384, 0, stream>>>(acc, counts, rw, (float*)d_out);
}